// Round 1
// baseline (1852.862 us; speedup 1.0000x reference)
//
#include <hip/hip_runtime.h>

typedef unsigned short bf16_t;
typedef __attribute__((ext_vector_type(8))) __bf16 bf16x8;
typedef __attribute__((ext_vector_type(4))) float f32x4;

__device__ __forceinline__ float bf2f(unsigned v) { return __uint_as_float(v << 16); }
__device__ __forceinline__ bf16_t f2bf(float f) {
  unsigned u = __float_as_uint(f);
  return (bf16_t)((u + 0x7fffu + ((u >> 16) & 1u)) >> 16);
}
__device__ __forceinline__ unsigned pack2(float a, float b) {
  return (unsigned)f2bf(a) | ((unsigned)f2bf(b) << 16);
}

// ---------- f32 -> bf16 converts ----------
__global__ void cvt_f32_bf16(const float* __restrict__ src, bf16_t* __restrict__ dst, long n4) {
  long i = (long)blockIdx.x * blockDim.x + threadIdx.x;
  if (i >= n4) return;
  float4 v = ((const float4*)src)[i];
  ((uint2*)dst)[i] = make_uint2(pack2(v.x, v.y), pack2(v.z, v.w));
}

// V-slice of enc_in_w: dst[l*H*H + r] = enc_in_w[l*3H*H + 2H*H + r]
__global__ void cvt_encv(const float* __restrict__ src, bf16_t* __restrict__ dst, long n4) {
  long i = (long)blockIdx.x * blockDim.x + threadIdx.x;
  if (i >= n4) return;  // n4 = 4*1024*1024/4
  const long per = (1024L * 1024L) / 4;
  long l = i / per, r = i % per;
  const float* s = src + l * 3 * 1024 * 1024 + 2 * 1024 * 1024 + r * 4;
  float4 v = *(const float4*)s;
  ((uint2*)dst)[i] = make_uint2(pack2(v.x, v.y), pack2(v.z, v.w));
}

// ---------- embedding gather (fp32 wte -> bf16 emb) ----------
__global__ void gather_emb(const int* __restrict__ tok, const float* __restrict__ wte,
                           bf16_t* __restrict__ emb) {
  long i = (long)blockIdx.x * blockDim.x + threadIdx.x;  // over 65536*192 groups of 4
  if (i >= 65536L * 192L) return;
  long nl = i / 192; int cg = (int)(i % 192);
  int t = tok[nl];
  float4 v = *(const float4*)(wte + (long)t * 768 + cg * 4);
  ((uint2*)emb)[i] = make_uint2(pack2(v.x, v.y), pack2(v.z, v.w));
}

// ---------- x_feats cast into x[:,0:256] + lens->float ----------
__global__ void xfeat_lenf(const float* __restrict__ xf, const int* __restrict__ lens,
                           bf16_t* __restrict__ x, float* __restrict__ lenf) {
  long i = (long)blockIdx.x * blockDim.x + threadIdx.x;
  if (i < 4096) lenf[i] = (float)lens[i];
  if (i >= 4096L * 64L) return;
  int row = (int)(i >> 6); int c4 = (int)(i & 63) * 4;
  float4 v = *(const float4*)(xf + (long)row * 256 + c4);
  *(uint2*)(x + (long)row * 1024 + c4) = make_uint2(pack2(v.x, v.y), pack2(v.z, v.w));
}

// ---------- generic bf16 MFMA GEMM: C[M,N](ldc) = A[M,K] @ W[N,K]^T + bias*rowscale ----------
#define BM 128
#define BN 128
#define BK 32

__device__ __forceinline__ void async16(const void* g, void* l) {
  __builtin_amdgcn_global_load_lds((const __attribute__((address_space(1))) void*)g,
                                   (__attribute__((address_space(3))) void*)l, 16, 0, 0);
}

template <bool RELU>
__global__ __launch_bounds__(256, 2) void gemm_bt(
    const bf16_t* __restrict__ A, const bf16_t* __restrict__ W,
    const float* __restrict__ bias, const float* __restrict__ rowscale,
    bf16_t* __restrict__ C, int M, int N, int K, int ldc) {
  __shared__ __attribute__((aligned(16))) bf16_t As[BM * BK];
  __shared__ __attribute__((aligned(16))) bf16_t Bs[BN * BK];
  const int t = threadIdx.x;
  const int m0 = blockIdx.y * BM;
  const int n0 = blockIdx.x * BN;
  const int lane = t & 63;
  const int wr = t >> 7;          // wave row 0..1
  const int wc = (t >> 6) & 1;    // wave col 0..1
  const int quad = lane >> 4;
  const int r16 = lane & 15;

  f32x4 acc[4][4] = {};

  const int c0 = t, c1 = t + 256;
  const int row0 = c0 >> 2, kp0 = (c0 & 3) << 3;
  const int row1 = c1 >> 2, kp1 = (c1 & 3) << 3;
  bf16_t* lA0 = As + (size_t)(c0 & ~63) * 8;
  bf16_t* lA1 = As + (size_t)(c1 & ~63) * 8;
  bf16_t* lB0 = Bs + (size_t)(c0 & ~63) * 8;
  bf16_t* lB1 = Bs + (size_t)(c1 & ~63) * 8;
  const bf16_t* Ab = A + (size_t)m0 * K;
  const bf16_t* Wb = W + (size_t)n0 * K;

  for (int k0 = 0; k0 < K; k0 += BK) {
    __syncthreads();
    async16(Ab + (size_t)row0 * K + k0 + kp0, lA0);
    async16(Ab + (size_t)row1 * K + k0 + kp1, lA1);
    async16(Wb + (size_t)row0 * K + k0 + kp0, lB0);
    async16(Wb + (size_t)row1 * K + k0 + kp1, lB1);
    __syncthreads();
    bf16x8 af[4], bfr[4];
#pragma unroll
    for (int i = 0; i < 4; i++) {
      af[i]  = *(const bf16x8*)(As + (wr * 64 + i * 16 + r16) * BK + quad * 8);
      bfr[i] = *(const bf16x8*)(Bs + (wc * 64 + i * 16 + r16) * BK + quad * 8);
    }
#pragma unroll
    for (int i = 0; i < 4; i++)
#pragma unroll
      for (int j = 0; j < 4; j++)
        acc[i][j] = __builtin_amdgcn_mfma_f32_16x16x32_bf16(af[i], bfr[j], acc[i][j], 0, 0, 0);
  }

  const int colb = n0 + wc * 64;
  const int rowb = m0 + wr * 64;
#pragma unroll
  for (int j = 0; j < 4; j++) {
    int col = colb + j * 16 + r16;
    float bv = bias ? bias[col] : 0.0f;
#pragma unroll
    for (int i = 0; i < 4; i++) {
      int rbase = rowb + i * 16 + quad * 4;
#pragma unroll
      for (int r = 0; r < 4; r++) {
        int row = rbase + r;
        float sc = rowscale ? rowscale[row] : 1.0f;
        float v = acc[i][j][r] + bv * sc;
        if (RELU) v = fmaxf(v, 0.0f);
        C[(size_t)row * ldc + col] = f2bf(v);
      }
    }
  }
}

// ---------- name attention: qkv[4096*16, 2304] -> s[4096, 768] = sum_{l<len} o_l ----------
__global__ __launch_bounds__(64) void attn_name(const bf16_t* __restrict__ qkv,
                                                const int* __restrict__ lens,
                                                bf16_t* __restrict__ s) {
  const int n = blockIdx.x, h = blockIdx.y;
  const int lane = threadIdx.x;
  __shared__ float qs[16][196];
  __shared__ float ks[16][196];
  __shared__ float vs[16][196];
  __shared__ float ps[16][16];
  __shared__ float wj[16];
  const int len = lens[n];
  const bf16_t* base = qkv + (size_t)n * 16 * 2304 + h * 192;
  for (int g = lane; g < 768; g += 64) {  // 16*192/4 groups
    int row = g / 48, c4 = (g % 48) * 4;
    const bf16_t* p = base + (size_t)row * 2304 + c4;
    uint2 a;
    a = *(const uint2*)p;
    qs[row][c4 + 0] = bf2f(a.x & 0xffff); qs[row][c4 + 1] = bf2f(a.x >> 16);
    qs[row][c4 + 2] = bf2f(a.y & 0xffff); qs[row][c4 + 3] = bf2f(a.y >> 16);
    a = *(const uint2*)(p + 768);
    ks[row][c4 + 0] = bf2f(a.x & 0xffff); ks[row][c4 + 1] = bf2f(a.x >> 16);
    ks[row][c4 + 2] = bf2f(a.y & 0xffff); ks[row][c4 + 3] = bf2f(a.y >> 16);
    a = *(const uint2*)(p + 1536);
    vs[row][c4 + 0] = bf2f(a.x & 0xffff); vs[row][c4 + 1] = bf2f(a.x >> 16);
    vs[row][c4 + 2] = bf2f(a.y & 0xffff); vs[row][c4 + 3] = bf2f(a.y >> 16);
  }
  __syncthreads();
  {
    const int l = lane >> 2, j0 = (lane & 3) * 4;
    float s0 = 0, s1 = 0, s2 = 0, s3 = 0;
    for (int d = 0; d < 192; d++) {
      float q = qs[l][d];
      s0 += q * ks[j0 + 0][d];
      s1 += q * ks[j0 + 1][d];
      s2 += q * ks[j0 + 2][d];
      s3 += q * ks[j0 + 3][d];
    }
    const float sc = 0.07216878f;  // 1/sqrt(192)
    ps[l][j0 + 0] = s0 * sc; ps[l][j0 + 1] = s1 * sc;
    ps[l][j0 + 2] = s2 * sc; ps[l][j0 + 3] = s3 * sc;
  }
  __syncthreads();
  if (lane < 16) {
    float m = -1e30f;
    for (int j = 0; j < len; j++) m = fmaxf(m, ps[lane][j]);
    float sum = 0.f;
    for (int j = 0; j < len; j++) sum += __expf(ps[lane][j] - m);
    float inv = 1.0f / sum;
    for (int j = 0; j < 16; j++) ps[lane][j] = (j < len) ? __expf(ps[lane][j] - m) * inv : 0.0f;
  }
  __syncthreads();
  if (lane < 16) {
    float a = 0.f;
    for (int l2 = 0; l2 < len; l2++) a += ps[l2][lane];
    wj[lane] = a;
  }
  __syncthreads();
  for (int d = lane; d < 192; d += 64) {
    float a = 0.f;
#pragma unroll
    for (int j = 0; j < 16; j++) a += wj[j] * vs[j][d];
    s[(size_t)n * 768 + h * 192 + d] = f2bf(a);
  }
}

// ---------- residual + layernorm (in place on h) ----------
__global__ __launch_bounds__(256) void ln_res(bf16_t* __restrict__ h, const bf16_t* __restrict__ d,
                                              const float* __restrict__ g, const float* __restrict__ b) {
  const int n = blockIdx.x, t = threadIdx.x;
  __shared__ float s1[4], s2[4];
  bf16_t* hr = h + (size_t)n * 1024;
  const bf16_t* dr = d + (size_t)n * 1024;
  float x[4];
  float sum = 0.f, ss = 0.f;
#pragma unroll
  for (int i = 0; i < 4; i++) {
    int c = t + i * 256;
    float v = bf2f(hr[c]) + bf2f(dr[c]);
    x[i] = v; sum += v; ss += v * v;
  }
#pragma unroll
  for (int o = 32; o > 0; o >>= 1) { sum += __shfl_down(sum, o); ss += __shfl_down(ss, o); }
  if ((t & 63) == 0) { s1[t >> 6] = sum; s2[t >> 6] = ss; }
  __syncthreads();
  sum = s1[0] + s1[1] + s1[2] + s1[3];
  ss  = s2[0] + s2[1] + s2[2] + s2[3];
  const float mean = sum * (1.0f / 1024.0f);
  const float var = ss * (1.0f / 1024.0f) - mean * mean;
  const float rstd = rsqrtf(var + 1e-5f);
#pragma unroll
  for (int i = 0; i < 4; i++) {
    int c = t + i * 256;
    hr[c] = f2bf((x[i] - mean) * rstd * g[c] + b[c]);
  }
}

// ---------- classifier head: out[4096,16] fp32 ----------
__global__ __launch_bounds__(256) void cls_head(const bf16_t* __restrict__ h,
                                                const float* __restrict__ cw,
                                                const float* __restrict__ cb,
                                                float* __restrict__ out) {
  const int n = blockIdx.x, t = threadIdx.x, wave = t >> 6, lane = t & 63;
  const bf16_t* hr = h + (size_t)n * 1024;
  for (int c = wave; c < 16; c += 4) {
    const float* wr = cw + c * 1024;
    float acc = 0.f;
    for (int i = lane; i < 1024; i += 64) acc += bf2f(hr[i]) * wr[i];
#pragma unroll
    for (int o = 32; o > 0; o >>= 1) acc += __shfl_down(acc, o);
    if (lane == 0) out[(size_t)n * 16 + c] = acc + cb[c];
  }
}

extern "C" void kernel_launch(void* const* d_in, const int* in_sizes, int n_in,
                              void* d_out, int out_size, void* d_ws, size_t ws_size,
                              hipStream_t stream) {
  (void)in_sizes; (void)n_in; (void)out_size; (void)ws_size;
  const int* name_tokens = (const int*)d_in[0];
  const int* name_lens   = (const int*)d_in[1];
  const float* x_feats   = (const float*)d_in[2];
  const float* wte       = (const float*)d_in[3];
  const float* mha_in_w  = (const float*)d_in[4];
  const float* mha_in_b  = (const float*)d_in[5];
  const float* mha_out_w = (const float*)d_in[6];
  const float* mha_out_b = (const float*)d_in[7];
  const float* bott_w    = (const float*)d_in[8];
  const float* bott_b    = (const float*)d_in[9];
  const float* enc_in_w  = (const float*)d_in[10];
  const float* enc_in_b  = (const float*)d_in[11];
  const float* enc_out_w = (const float*)d_in[12];
  const float* enc_out_b = (const float*)d_in[13];
  const float* enc_ln1_g = (const float*)d_in[14];
  const float* enc_ln1_b = (const float*)d_in[15];
  const float* enc_ln2_g = (const float*)d_in[16];
  const float* enc_ln2_b = (const float*)d_in[17];
  const float* enc_ff1_w = (const float*)d_in[18];
  const float* enc_ff1_b = (const float*)d_in[19];
  const float* enc_ff2_w = (const float*)d_in[20];
  const float* enc_ff2_b = (const float*)d_in[21];
  const float* cls_w     = (const float*)d_in[22];
  const float* cls_b     = (const float*)d_in[23];
  float* out = (float*)d_out;

  char* base = (char*)d_ws;
  size_t off = 0;
  auto alloc = [&](size_t bytes) -> char* {
    char* p = base + off;
    off = (off + bytes + 255) & ~(size_t)255;
    return p;
  };
  bf16_t* w_qkv  = (bf16_t*)alloc((size_t)2304 * 768 * 2);
  bf16_t* w_out  = (bf16_t*)alloc((size_t)768 * 768 * 2);
  bf16_t* w_bott = (bf16_t*)alloc((size_t)1024 * 1024 * 2);
  bf16_t* w_encv = (bf16_t*)alloc((size_t)4 * 1024 * 1024 * 2);
  bf16_t* w_enco = (bf16_t*)alloc((size_t)4 * 1024 * 1024 * 2);
  bf16_t* w_ff1  = (bf16_t*)alloc((size_t)4 * 2048 * 1024 * 2);
  bf16_t* w_ff2  = (bf16_t*)alloc((size_t)4 * 1024 * 2048 * 2);
  float*  lenf   = (float*)alloc((size_t)4096 * 4);
  char* reuse = alloc((size_t)65536 * 768 * 2);  // emb region, reused after QKV GEMM
  bf16_t* emb = (bf16_t*)reuse;
  bf16_t* s_  = (bf16_t*)reuse;                            // 4096x768
  bf16_t* x_  = (bf16_t*)(reuse + 6291456);                // 4096x1024
  bf16_t* h_  = (bf16_t*)(reuse + 6291456 + 8388608);      // 4096x1024
  bf16_t* v_  = (bf16_t*)(reuse + 6291456 + 2 * 8388608);  // 4096x1024
  bf16_t* a_  = (bf16_t*)(reuse + 6291456 + 3 * 8388608);  // 4096x1024
  bf16_t* f1_ = (bf16_t*)(reuse + 6291456 + 4 * 8388608);  // 4096x2048
  bf16_t* qkv = (bf16_t*)alloc((size_t)65536 * 2304 * 2);

  dim3 b256(256);
  auto g1 = [](long n4) { return dim3((unsigned)((n4 + 255) / 256)); };

  // weight converts
  cvt_f32_bf16<<<g1(442368), b256, 0, stream>>>(mha_in_w, w_qkv, 442368L);
  cvt_f32_bf16<<<g1(147456), b256, 0, stream>>>(mha_out_w, w_out, 147456L);
  cvt_f32_bf16<<<g1(262144), b256, 0, stream>>>(bott_w, w_bott, 262144L);
  cvt_encv<<<g1(1048576), b256, 0, stream>>>(enc_in_w, w_encv, 1048576L);
  cvt_f32_bf16<<<g1(1048576), b256, 0, stream>>>(enc_out_w, w_enco, 1048576L);
  cvt_f32_bf16<<<g1(2097152), b256, 0, stream>>>(enc_ff1_w, w_ff1, 2097152L);
  cvt_f32_bf16<<<g1(2097152), b256, 0, stream>>>(enc_ff2_w, w_ff2, 2097152L);

  // stage A
  gather_emb<<<dim3(49152), b256, 0, stream>>>(name_tokens, wte, emb);
  gemm_bt<false><<<dim3(18, 512), b256, 0, stream>>>(emb, w_qkv, mha_in_b, (const float*)nullptr,
                                                     qkv, 65536, 2304, 768, 2304);
  xfeat_lenf<<<dim3(1024), b256, 0, stream>>>(x_feats, name_lens, x_, lenf);
  attn_name<<<dim3(4096, 4), dim3(64), 0, stream>>>(qkv, name_lens, s_);
  gemm_bt<false><<<dim3(6, 32), b256, 0, stream>>>(s_, w_out, mha_out_b, lenf,
                                                   x_ + 256, 4096, 768, 768, 1024);
  gemm_bt<false><<<dim3(8, 32), b256, 0, stream>>>(x_, w_bott, bott_b, (const float*)nullptr,
                                                   h_, 4096, 1024, 1024, 1024);
  // encoder layers (seq len 1: attention == V then out-proj)
  for (int l = 0; l < 4; l++) {
    gemm_bt<false><<<dim3(8, 32), b256, 0, stream>>>(
        h_, w_encv + (size_t)l * 1024 * 1024, enc_in_b + l * 3072 + 2048,
        (const float*)nullptr, v_, 4096, 1024, 1024, 1024);
    gemm_bt<false><<<dim3(8, 32), b256, 0, stream>>>(
        v_, w_enco + (size_t)l * 1024 * 1024, enc_out_b + l * 1024,
        (const float*)nullptr, a_, 4096, 1024, 1024, 1024);
    ln_res<<<dim3(4096), b256, 0, stream>>>(h_, a_, enc_ln1_g + l * 1024, enc_ln1_b + l * 1024);
    gemm_bt<true><<<dim3(16, 32), b256, 0, stream>>>(
        h_, w_ff1 + (size_t)l * 2048 * 1024, enc_ff1_b + l * 2048,
        (const float*)nullptr, f1_, 4096, 2048, 1024, 2048);
    gemm_bt<false><<<dim3(8, 32), b256, 0, stream>>>(
        f1_, w_ff2 + (size_t)l * 1024 * 2048, enc_ff2_b + l * 1024,
        (const float*)nullptr, v_, 4096, 1024, 2048, 1024);
    ln_res<<<dim3(4096), b256, 0, stream>>>(h_, v_, enc_ln2_g + l * 1024, enc_ln2_b + l * 1024);
  }
  cls_head<<<dim3(4096), b256, 0, stream>>>(h_, cls_w, cls_b, out);
}

// Round 2
// 1223.619 us; speedup vs baseline: 1.5142x; 1.5142x over previous
//
#include <hip/hip_runtime.h>

typedef unsigned short bf16_t;
typedef __attribute__((ext_vector_type(8))) __bf16 bf16x8;
typedef __attribute__((ext_vector_type(4))) float f32x4;

__device__ __forceinline__ float bf2f(unsigned v) { return __uint_as_float(v << 16); }
__device__ __forceinline__ bf16_t f2bf(float f) {
  unsigned u = __float_as_uint(f);
  return (bf16_t)((u + 0x7fffu + ((u >> 16) & 1u)) >> 16);
}
__device__ __forceinline__ unsigned pack2(float a, float b) {
  return (unsigned)f2bf(a) | ((unsigned)f2bf(b) << 16);
}

// ---------- exclusive scan of name_lens (4096 = 256 threads x 16) ----------
__global__ __launch_bounds__(256) void scan_lens(const int* __restrict__ lens,
                                                 int* __restrict__ offs,
                                                 int* __restrict__ Mact) {
  __shared__ int wsum[4];
  const int t = threadIdx.x;
  int v[16]; int s = 0;
#pragma unroll
  for (int i = 0; i < 16; i++) { v[i] = lens[t * 16 + i]; s += v[i]; }
  const int lane = t & 63, w = t >> 6;
  int x = s;
#pragma unroll
  for (int o = 1; o < 64; o <<= 1) {
    int y = __shfl_up(x, o);
    if (lane >= o) x += y;
  }
  if (lane == 63) wsum[w] = x;
  __syncthreads();
  int base = 0;
  for (int i = 0; i < w; i++) base += wsum[i];
  int run = base + x - s;  // exclusive prefix of this thread's chunk
#pragma unroll
  for (int i = 0; i < 16; i++) { offs[t * 16 + i] = run; run += v[i]; }
  if (t == 255) Mact[0] = run;
}

// ---------- f32 -> bf16 converts ----------
__global__ void cvt_f32_bf16(const float* __restrict__ src, bf16_t* __restrict__ dst, long n4) {
  long i = (long)blockIdx.x * blockDim.x + threadIdx.x;
  if (i >= n4) return;
  float4 v = ((const float4*)src)[i];
  ((uint2*)dst)[i] = make_uint2(pack2(v.x, v.y), pack2(v.z, v.w));
}

__global__ void cvt_encv(const float* __restrict__ src, bf16_t* __restrict__ dst, long n4) {
  long i = (long)blockIdx.x * blockDim.x + threadIdx.x;
  if (i >= n4) return;
  const long per = (1024L * 1024L) / 4;
  long l = i / per, r = i % per;
  const float* s = src + l * 3 * 1024 * 1024 + 2 * 1024 * 1024 + r * 4;
  float4 v = *(const float4*)s;
  ((uint2*)dst)[i] = make_uint2(pack2(v.x, v.y), pack2(v.z, v.w));
}

// ---------- compacted embedding gather ----------
__global__ void gather_emb_c(const int* __restrict__ tok, const int* __restrict__ lens,
                             const int* __restrict__ offs, const float* __restrict__ wte,
                             bf16_t* __restrict__ emb) {
  long i = (long)blockIdx.x * blockDim.x + threadIdx.x;  // 65536*192
  if (i >= 65536L * 192L) return;
  long nl = i / 192; int cg = (int)(i % 192);
  int n = (int)(nl >> 4), l = (int)(nl & 15);
  if (l >= lens[n]) return;
  long ro = (long)offs[n] + l;
  int t = tok[nl];
  float4 v = *(const float4*)(wte + (long)t * 768 + cg * 4);
  ((uint2*)emb)[ro * 192 + cg] = make_uint2(pack2(v.x, v.y), pack2(v.z, v.w));
}

// ---------- x_feats cast into x[:,0:256] + lens->float ----------
__global__ void xfeat_lenf(const float* __restrict__ xf, const int* __restrict__ lens,
                           bf16_t* __restrict__ x, float* __restrict__ lenf) {
  long i = (long)blockIdx.x * blockDim.x + threadIdx.x;
  if (i < 4096) lenf[i] = (float)lens[i];
  if (i >= 4096L * 64L) return;
  int row = (int)(i >> 6); int c4 = (int)(i & 63) * 4;
  float4 v = *(const float4*)(xf + (long)row * 256 + c4);
  *(uint2*)(x + (long)row * 1024 + c4) = make_uint2(pack2(v.x, v.y), pack2(v.z, v.w));
}

// ---------- 128x128 MFMA GEMM (large-M): C = A @ W^T + bias ----------
#define BM 128
#define BN 128
#define BK 32

__device__ __forceinline__ void async16(const void* g, void* l) {
  __builtin_amdgcn_global_load_lds((const __attribute__((address_space(1))) void*)g,
                                   (__attribute__((address_space(3))) void*)l, 16, 0, 0);
}

__global__ __launch_bounds__(256, 2) void gemm_bt(
    const bf16_t* __restrict__ A, const bf16_t* __restrict__ W,
    const float* __restrict__ bias, bf16_t* __restrict__ C,
    int K, int ldc, const int* __restrict__ Mp) {
  const int m0 = blockIdx.y * BM;
  if (m0 >= *Mp) return;  // compaction early-exit (block-uniform)
  __shared__ __attribute__((aligned(16))) bf16_t As[BM * BK];
  __shared__ __attribute__((aligned(16))) bf16_t Bs[BN * BK];
  const int t = threadIdx.x;
  const int n0 = blockIdx.x * BN;
  const int lane = t & 63;
  const int wr = t >> 7;
  const int wc = (t >> 6) & 1;
  const int quad = lane >> 4;
  const int r16 = lane & 15;

  f32x4 acc[4][4] = {};

  const int c0 = t, c1 = t + 256;
  const int row0 = c0 >> 2, kp0 = (c0 & 3) << 3;
  const int row1 = c1 >> 2, kp1 = (c1 & 3) << 3;
  bf16_t* lA0 = As + (size_t)(c0 & ~63) * 8;
  bf16_t* lA1 = As + (size_t)(c1 & ~63) * 8;
  bf16_t* lB0 = Bs + (size_t)(c0 & ~63) * 8;
  bf16_t* lB1 = Bs + (size_t)(c1 & ~63) * 8;
  const bf16_t* Ab = A + (size_t)m0 * K;
  const bf16_t* Wb = W + (size_t)n0 * K;

  for (int k0 = 0; k0 < K; k0 += BK) {
    __syncthreads();
    async16(Ab + (size_t)row0 * K + k0 + kp0, lA0);
    async16(Ab + (size_t)row1 * K + k0 + kp1, lA1);
    async16(Wb + (size_t)row0 * K + k0 + kp0, lB0);
    async16(Wb + (size_t)row1 * K + k0 + kp1, lB1);
    __syncthreads();
    bf16x8 af[4], bfr[4];
#pragma unroll
    for (int i = 0; i < 4; i++) {
      af[i]  = *(const bf16x8*)(As + (wr * 64 + i * 16 + r16) * BK + quad * 8);
      bfr[i] = *(const bf16x8*)(Bs + (wc * 64 + i * 16 + r16) * BK + quad * 8);
    }
#pragma unroll
    for (int i = 0; i < 4; i++)
#pragma unroll
      for (int j = 0; j < 4; j++)
        acc[i][j] = __builtin_amdgcn_mfma_f32_16x16x32_bf16(af[i], bfr[j], acc[i][j], 0, 0, 0);
  }

  const int colb = n0 + wc * 64;
  const int rowb = m0 + wr * 64;
#pragma unroll
  for (int j = 0; j < 4; j++) {
    int col = colb + j * 16 + r16;
    float bv = bias ? bias[col] : 0.0f;
#pragma unroll
    for (int i = 0; i < 4; i++) {
      int rbase = rowb + i * 16 + quad * 4;
#pragma unroll
      for (int r = 0; r < 4; r++) {
        int row = rbase + r;
        C[(size_t)row * ldc + col] = f2bf(acc[i][j][r] + bv);
      }
    }
  }
}

// ---------- 64x64 MFMA GEMM (small-M, high block count), XOR-swizzled LDS ----------
template <bool RELU>
__global__ __launch_bounds__(256, 4) void gemm64(
    const bf16_t* __restrict__ A, const bf16_t* __restrict__ W,
    const float* __restrict__ bias, const float* __restrict__ rowscale,
    bf16_t* __restrict__ C, int K, int ldc) {
  __shared__ __attribute__((aligned(16))) bf16_t As[64 * 64];
  __shared__ __attribute__((aligned(16))) bf16_t Bs[64 * 64];
  const int t = threadIdx.x;
  const int m0 = blockIdx.y * 64, n0 = blockIdx.x * 64;
  const int lane = t & 63, wr = t >> 7, wc = (t >> 6) & 1;
  const int quad = lane >> 4, r16 = lane & 15;
  f32x4 acc[2][2] = {};
  // staging: 512 chunks of 16B per matrix; chunk c -> LDS elem offset c*8,
  // holds row (c>>3), k-chunk ((c&7) ^ (row&7))  [XOR swizzle for bank spread]
  const int c0 = t, c1 = t + 256;
  const int row0 = c0 >> 3, kp0 = (((c0 & 7) ^ (row0 & 7)) << 3);
  const int row1 = c1 >> 3, kp1 = (((c1 & 7) ^ (row1 & 7)) << 3);
  bf16_t* lA0 = As + (size_t)(c0 & ~63) * 8;
  bf16_t* lA1 = As + (size_t)(c1 & ~63) * 8;
  bf16_t* lB0 = Bs + (size_t)(c0 & ~63) * 8;
  bf16_t* lB1 = Bs + (size_t)(c1 & ~63) * 8;
  const bf16_t* Ab = A + (size_t)m0 * K;
  const bf16_t* Wb = W + (size_t)n0 * K;

  for (int k0 = 0; k0 < K; k0 += 64) {
    __syncthreads();
    async16(Ab + (size_t)row0 * K + k0 + kp0, lA0);
    async16(Ab + (size_t)row1 * K + k0 + kp1, lA1);
    async16(Wb + (size_t)row0 * K + k0 + kp0, lB0);
    async16(Wb + (size_t)row1 * K + k0 + kp1, lB1);
    __syncthreads();
#pragma unroll
    for (int kk8 = 0; kk8 < 8; kk8 += 4) {
      bf16x8 af[2], bfr[2];
#pragma unroll
      for (int i = 0; i < 2; i++) {
        int Ra = wr * 32 + i * 16 + r16;
        af[i] = *(const bf16x8*)(As + Ra * 64 + (((kk8 + quad) ^ (Ra & 7)) << 3));
        int Rb = wc * 32 + i * 16 + r16;
        bfr[i] = *(const bf16x8*)(Bs + Rb * 64 + (((kk8 + quad) ^ (Rb & 7)) << 3));
      }
#pragma unroll
      for (int i = 0; i < 2; i++)
#pragma unroll
        for (int j = 0; j < 2; j++)
          acc[i][j] = __builtin_amdgcn_mfma_f32_16x16x32_bf16(af[i], bfr[j], acc[i][j], 0, 0, 0);
    }
  }

  const int colb = n0 + wc * 32, rowb = m0 + wr * 32;
#pragma unroll
  for (int j = 0; j < 2; j++) {
    int col = colb + j * 16 + r16;
    float bv = bias ? bias[col] : 0.0f;
#pragma unroll
    for (int i = 0; i < 2; i++) {
      int rbase = rowb + i * 16 + quad * 4;
#pragma unroll
      for (int r = 0; r < 4; r++) {
        int row = rbase + r;
        float sc = rowscale ? rowscale[row] : 1.0f;
        float v = acc[i][j][r] + bv * sc;
        if (RELU) v = fmaxf(v, 0.0f);
        C[(size_t)row * ldc + col] = f2bf(v);
      }
    }
  }
}

// ---------- name attention on compacted qkv ----------
__global__ __launch_bounds__(64) void attn_name(const bf16_t* __restrict__ qkv,
                                                const int* __restrict__ lens,
                                                const int* __restrict__ offs,
                                                bf16_t* __restrict__ s) {
  const int n = blockIdx.x, h = blockIdx.y;
  const int lane = threadIdx.x;
  __shared__ unsigned short qs[16][208];
  __shared__ unsigned short ks[16][208];
  __shared__ unsigned short vs[16][208];
  __shared__ float ps[16][16];
  __shared__ float wj[16];
  const int len = lens[n];
  const bf16_t* base = qkv + (size_t)offs[n] * 2304 + h * 192;
  for (int g = lane; g < len * 48; g += 64) {
    int row = g / 48, c4 = (g % 48) * 4;
    const bf16_t* p = base + (size_t)row * 2304 + c4;
    uint2 a;
    a = *(const uint2*)p;
    *(unsigned*)&qs[row][c4] = a.x; *(unsigned*)&qs[row][c4 + 2] = a.y;
    a = *(const uint2*)(p + 768);
    *(unsigned*)&ks[row][c4] = a.x; *(unsigned*)&ks[row][c4 + 2] = a.y;
    a = *(const uint2*)(p + 1536);
    *(unsigned*)&vs[row][c4] = a.x; *(unsigned*)&vs[row][c4 + 2] = a.y;
  }
  __syncthreads();
  {
    const int l = lane >> 2, j0 = (lane & 3) * 4;
    float s0 = 0, s1 = 0, s2 = 0, s3 = 0;
    for (int d = 0; d < 192; d++) {
      float q = bf2f(qs[l][d]);
      s0 += q * bf2f(ks[j0 + 0][d]);
      s1 += q * bf2f(ks[j0 + 1][d]);
      s2 += q * bf2f(ks[j0 + 2][d]);
      s3 += q * bf2f(ks[j0 + 3][d]);
    }
    const float sc = 0.07216878f;  // 1/sqrt(192)
    ps[l][j0 + 0] = s0 * sc; ps[l][j0 + 1] = s1 * sc;
    ps[l][j0 + 2] = s2 * sc; ps[l][j0 + 3] = s3 * sc;
  }
  __syncthreads();
  if (lane < 16) {
    float m = -1e30f;
    for (int j = 0; j < len; j++) m = fmaxf(m, ps[lane][j]);
    float sum = 0.f;
    for (int j = 0; j < len; j++) sum += __expf(ps[lane][j] - m);
    float inv = 1.0f / sum;
    for (int j = 0; j < 16; j++) ps[lane][j] = (j < len) ? __expf(ps[lane][j] - m) * inv : 0.0f;
  }
  __syncthreads();
  if (lane < 16) {
    float a = 0.f;
    for (int l2 = 0; l2 < len; l2++) a += ps[l2][lane];
    wj[lane] = a;
  }
  __syncthreads();
  for (int d = lane; d < 192; d += 64) {
    float a = 0.f;
    for (int j = 0; j < len; j++) a += wj[j] * bf2f(vs[j][d]);
    s[(size_t)n * 768 + h * 192 + d] = f2bf(a);
  }
}

// ---------- residual + layernorm (in place on h) ----------
__global__ __launch_bounds__(256) void ln_res(bf16_t* __restrict__ h, const bf16_t* __restrict__ d,
                                              const float* __restrict__ g, const float* __restrict__ b) {
  const int n = blockIdx.x, t = threadIdx.x;
  __shared__ float s1[4], s2[4];
  bf16_t* hr = h + (size_t)n * 1024;
  const bf16_t* dr = d + (size_t)n * 1024;
  float x[4];
  float sum = 0.f, ss = 0.f;
#pragma unroll
  for (int i = 0; i < 4; i++) {
    int c = t + i * 256;
    float v = bf2f(hr[c]) + bf2f(dr[c]);
    x[i] = v; sum += v; ss += v * v;
  }
#pragma unroll
  for (int o = 32; o > 0; o >>= 1) { sum += __shfl_down(sum, o); ss += __shfl_down(ss, o); }
  if ((t & 63) == 0) { s1[t >> 6] = sum; s2[t >> 6] = ss; }
  __syncthreads();
  sum = s1[0] + s1[1] + s1[2] + s1[3];
  ss  = s2[0] + s2[1] + s2[2] + s2[3];
  const float mean = sum * (1.0f / 1024.0f);
  const float var = ss * (1.0f / 1024.0f) - mean * mean;
  const float rstd = rsqrtf(var + 1e-5f);
#pragma unroll
  for (int i = 0; i < 4; i++) {
    int c = t + i * 256;
    hr[c] = f2bf((x[i] - mean) * rstd * g[c] + b[c]);
  }
}

// ---------- classifier head ----------
__global__ __launch_bounds__(256) void cls_head(const bf16_t* __restrict__ h,
                                                const float* __restrict__ cw,
                                                const float* __restrict__ cb,
                                                float* __restrict__ out) {
  const int n = blockIdx.x, t = threadIdx.x, wave = t >> 6, lane = t & 63;
  const bf16_t* hr = h + (size_t)n * 1024;
  for (int c = wave; c < 16; c += 4) {
    const float* wr = cw + c * 1024;
    float acc = 0.f;
    for (int i = lane; i < 1024; i += 64) acc += bf2f(hr[i]) * wr[i];
#pragma unroll
    for (int o = 32; o > 0; o >>= 1) acc += __shfl_down(acc, o);
    if (lane == 0) out[(size_t)n * 16 + c] = acc + cb[c];
  }
}

extern "C" void kernel_launch(void* const* d_in, const int* in_sizes, int n_in,
                              void* d_out, int out_size, void* d_ws, size_t ws_size,
                              hipStream_t stream) {
  (void)in_sizes; (void)n_in; (void)out_size; (void)ws_size;
  const int* name_tokens = (const int*)d_in[0];
  const int* name_lens   = (const int*)d_in[1];
  const float* x_feats   = (const float*)d_in[2];
  const float* wte       = (const float*)d_in[3];
  const float* mha_in_w  = (const float*)d_in[4];
  const float* mha_in_b  = (const float*)d_in[5];
  const float* mha_out_w = (const float*)d_in[6];
  const float* mha_out_b = (const float*)d_in[7];
  const float* bott_w    = (const float*)d_in[8];
  const float* bott_b    = (const float*)d_in[9];
  const float* enc_in_w  = (const float*)d_in[10];
  const float* enc_in_b  = (const float*)d_in[11];
  const float* enc_out_w = (const float*)d_in[12];
  const float* enc_out_b = (const float*)d_in[13];
  const float* enc_ln1_g = (const float*)d_in[14];
  const float* enc_ln1_b = (const float*)d_in[15];
  const float* enc_ln2_g = (const float*)d_in[16];
  const float* enc_ln2_b = (const float*)d_in[17];
  const float* enc_ff1_w = (const float*)d_in[18];
  const float* enc_ff1_b = (const float*)d_in[19];
  const float* enc_ff2_w = (const float*)d_in[20];
  const float* enc_ff2_b = (const float*)d_in[21];
  const float* cls_w     = (const float*)d_in[22];
  const float* cls_b     = (const float*)d_in[23];
  float* out = (float*)d_out;

  char* base = (char*)d_ws;
  size_t off = 0;
  auto alloc = [&](size_t bytes) -> char* {
    char* p = base + off;
    off = (off + bytes + 255) & ~(size_t)255;
    return p;
  };
  bf16_t* w_qkv  = (bf16_t*)alloc((size_t)2304 * 768 * 2);
  bf16_t* w_out  = (bf16_t*)alloc((size_t)768 * 768 * 2);
  bf16_t* w_bott = (bf16_t*)alloc((size_t)1024 * 1024 * 2);
  bf16_t* w_encv = (bf16_t*)alloc((size_t)4 * 1024 * 1024 * 2);
  bf16_t* w_enco = (bf16_t*)alloc((size_t)4 * 1024 * 1024 * 2);
  bf16_t* w_ff1  = (bf16_t*)alloc((size_t)4 * 2048 * 1024 * 2);
  bf16_t* w_ff2  = (bf16_t*)alloc((size_t)4 * 1024 * 2048 * 2);
  float*  lenf   = (float*)alloc((size_t)4096 * 4);
  int*    offs   = (int*)alloc((size_t)4096 * 4);
  int*    Mact   = (int*)alloc((size_t)256);
  char* reuse = alloc((size_t)65536 * 768 * 2);  // emb region, reused after QKV GEMM
  bf16_t* emb = (bf16_t*)reuse;
  bf16_t* s_  = (bf16_t*)reuse;                            // 4096x768
  bf16_t* x_  = (bf16_t*)(reuse + 6291456);                // 4096x1024
  bf16_t* h_  = (bf16_t*)(reuse + 6291456 + 8388608);      // 4096x1024
  bf16_t* v_  = (bf16_t*)(reuse + 6291456 + 2 * 8388608);  // 4096x1024
  bf16_t* a_  = (bf16_t*)(reuse + 6291456 + 3 * 8388608);  // 4096x1024
  bf16_t* f1_ = (bf16_t*)(reuse + 6291456 + 4 * 8388608);  // 4096x2048
  bf16_t* qkv = (bf16_t*)alloc((size_t)65536 * 2304 * 2);

  dim3 b256(256);
  auto g1 = [](long n4) { return dim3((unsigned)((n4 + 255) / 256)); };

  scan_lens<<<dim3(1), b256, 0, stream>>>(name_lens, offs, Mact);

  // weight converts
  cvt_f32_bf16<<<g1(442368), b256, 0, stream>>>(mha_in_w, w_qkv, 442368L);
  cvt_f32_bf16<<<g1(147456), b256, 0, stream>>>(mha_out_w, w_out, 147456L);
  cvt_f32_bf16<<<g1(262144), b256, 0, stream>>>(bott_w, w_bott, 262144L);
  cvt_encv<<<g1(1048576), b256, 0, stream>>>(enc_in_w, w_encv, 1048576L);
  cvt_f32_bf16<<<g1(1048576), b256, 0, stream>>>(enc_out_w, w_enco, 1048576L);
  cvt_f32_bf16<<<g1(2097152), b256, 0, stream>>>(enc_ff1_w, w_ff1, 2097152L);
  cvt_f32_bf16<<<g1(2097152), b256, 0, stream>>>(enc_ff2_w, w_ff2, 2097152L);

  // stage A (compacted rows)
  gather_emb_c<<<dim3(49152), b256, 0, stream>>>(name_tokens, name_lens, offs, wte, emb);
  gemm_bt<<<dim3(18, 512), b256, 0, stream>>>(emb, w_qkv, mha_in_b, qkv, 768, 2304, Mact);
  xfeat_lenf<<<dim3(1024), b256, 0, stream>>>(x_feats, name_lens, x_, lenf);
  attn_name<<<dim3(4096, 4), dim3(64), 0, stream>>>(qkv, name_lens, offs, s_);
  gemm64<false><<<dim3(12, 64), b256, 0, stream>>>(s_, w_out, mha_out_b, lenf,
                                                   x_ + 256, 768, 1024);
  gemm64<false><<<dim3(16, 64), b256, 0, stream>>>(x_, w_bott, bott_b, (const float*)nullptr,
                                                   h_, 1024, 1024);
  // encoder layers (seq len 1: attention == V-proj then out-proj)
  for (int l = 0; l < 4; l++) {
    gemm64<false><<<dim3(16, 64), b256, 0, stream>>>(
        h_, w_encv + (size_t)l * 1024 * 1024, enc_in_b + l * 3072 + 2048,
        (const float*)nullptr, v_, 1024, 1024);
    gemm64<false><<<dim3(16, 64), b256, 0, stream>>>(
        v_, w_enco + (size_t)l * 1024 * 1024, enc_out_b + l * 1024,
        (const float*)nullptr, a_, 1024, 1024);
    ln_res<<<dim3(4096), b256, 0, stream>>>(h_, a_, enc_ln1_g + l * 1024, enc_ln1_b + l * 1024);
    gemm64<true><<<dim3(32, 64), b256, 0, stream>>>(
        h_, w_ff1 + (size_t)l * 2048 * 1024, enc_ff1_b + l * 2048,
        (const float*)nullptr, f1_, 1024, 2048);
    gemm64<false><<<dim3(16, 64), b256, 0, stream>>>(
        f1_, w_ff2 + (size_t)l * 1024 * 2048, enc_ff2_b + l * 1024,
        (const float*)nullptr, v_, 2048, 1024);
    ln_res<<<dim3(4096), b256, 0, stream>>>(h_, v_, enc_ln2_g + l * 1024, enc_ln2_b + l * 1024);
  }
  cls_head<<<dim3(4096), b256, 0, stream>>>(h_, cls_w, cls_b, out);
}